// Round 1
// baseline (224.525 us; speedup 1.0000x reference)
//
#include <hip/hip_runtime.h>

#define S_LEN 256
#define H_DIM 768
#define T_HEADS 13
#define WN 1664
#define NEGV 1.0e12f

typedef __bf16 bf16x8 __attribute__((ext_vector_type(8)));
typedef float f32x4 __attribute__((ext_vector_type(4)));

static __device__ __forceinline__ ushort f2bf(float x) {
  unsigned u = __float_as_uint(x);
  unsigned r = (u + 0x7FFFu + ((u >> 16) & 1u)) >> 16;
  return (ushort)r;
}

__global__ __launch_bounds__(256, 1) void gp_kernel(
    const float* __restrict__ lhs, const float* __restrict__ Wd,
    const float* __restrict__ bias, const float* __restrict__ amask,
    float* __restrict__ out) {
  const int bid = blockIdx.x;
  const int b = bid / T_HEADS;
  const int th = bid % T_HEADS;
  const int wcol0 = th * 128;
  const int tid = threadIdx.x;
  const int w = tid >> 6;
  const int lane = tid & 63;
  const int lo = lane & 15;
  const int hi = lane >> 4;

  // LDS: 20K + 10K + 36K + 36K + 1K = ~103 KB -> 1 block/CU
  __shared__ ushort A_s[256][40];   // lhs chunk, rows padded to 40 bf16
  __shared__ ushort W_sT[128][40];  // W chunk transposed [col][k]
  __shared__ ushort Q_s[256][72];   // rope'd Q, padded rows
  __shared__ ushort K_s[256][72];   // rope'd K
  __shared__ float mask_s[256];

  mask_s[tid] = amask[b * S_LEN + tid];

  f32x4 acc[4][8];
#pragma unroll
  for (int mi = 0; mi < 4; ++mi)
#pragma unroll
    for (int ni = 0; ni < 8; ++ni) acc[mi][ni] = (f32x4){0.f, 0.f, 0.f, 0.f};

  const float* Ab = lhs + (size_t)b * (S_LEN * H_DIM);
  const int wc = tid & 127;    // W stage: column within head slice
  const int whalf = tid >> 7;  // W stage: which 16-row half

  // ---------------- phase 1: P = lhs[b] @ W[:, t*128 : t*128+128] ----------------
  for (int k0 = 0; k0 < H_DIM; k0 += 32) {
    // stage A chunk 256x32 f32->bf16 (8 float4 per thread, coalesced 128B/8lanes)
#pragma unroll
    for (int p = 0; p < 8; ++p) {
      int f = p * 256 + tid;
      int m = f >> 3;
      int c4 = f & 7;
      float4 v = *reinterpret_cast<const float4*>(Ab + (size_t)m * H_DIM + k0 + c4 * 4);
      ushort4 u = make_ushort4(f2bf(v.x), f2bf(v.y), f2bf(v.z), f2bf(v.w));
      *reinterpret_cast<ushort4*>(&A_s[m][c4 * 4]) = u;
    }
    // stage W chunk transposed: W_sT[c][r] = W[k0+r][wcol0+c]; global reads coalesced over c
    ushort wtmp[16];
#pragma unroll
    for (int r16 = 0; r16 < 16; ++r16) {
      int r = whalf * 16 + r16;
      wtmp[r16] = f2bf(Wd[(size_t)(k0 + r) * WN + wcol0 + wc]);
    }
#pragma unroll
    for (int q = 0; q < 4; ++q) {
      ushort4 u = make_ushort4(wtmp[q * 4], wtmp[q * 4 + 1], wtmp[q * 4 + 2], wtmp[q * 4 + 3]);
      *reinterpret_cast<ushort4*>(&W_sT[wc][whalf * 16 + q * 4]) = u;
    }
    __syncthreads();

    // fragments: A row = lo, k = hi*8+i ; B col = lo, same k mapping (consistent-k)
    bf16x8 af[4];
#pragma unroll
    for (int mi = 0; mi < 4; ++mi)
      af[mi] = *reinterpret_cast<const bf16x8*>(&A_s[w * 64 + mi * 16 + lo][hi * 8]);
#pragma unroll
    for (int ni = 0; ni < 8; ++ni) {
      bf16x8 bfr = *reinterpret_cast<const bf16x8*>(&W_sT[ni * 16 + lo][hi * 8]);
#pragma unroll
      for (int mi = 0; mi < 4; ++mi)
        acc[mi][ni] = __builtin_amdgcn_mfma_f32_16x16x32_bf16(af[mi], bfr, acc[mi][ni], 0, 0, 0);
    }
    __syncthreads();
  }

  // ---------------- bias + RoPE + write Q/K to LDS ----------------
  float bj[8];
#pragma unroll
  for (int ni = 0; ni < 8; ++ni) bj[ni] = bias[wcol0 + ni * 16 + lo];

  // i = ((col & 63) >> 1); per lane the 4 N-frag groups give i = ii*8 + (lo>>1)
  float inv_[4];
#pragma unroll
  for (int ii = 0; ii < 4; ++ii)
    inv_[ii] = exp2f(-(float)(ii * 8 + (lo >> 1)) * 0.4152410118609203f);  // log2(1e4)/32
  const float sgn = (lo & 1) ? 1.0f : -1.0f;

#pragma unroll
  for (int mi = 0; mi < 4; ++mi) {
#pragma unroll
    for (int r = 0; r < 4; ++r) {
      int m = w * 64 + mi * 16 + hi * 4 + r;  // C/D row mapping (verified)
#pragma unroll
      for (int ii = 0; ii < 4; ++ii) {
        float sv, cv;
        __sincosf((float)m * inv_[ii], &sv, &cv);
        {  // q half: cols 0..63
          float v = acc[mi][ii][r] + bj[ii];
          float o = __shfl_xor(v, 1);  // partner column (col^1)
          Q_s[m][ii * 16 + lo] = f2bf(v * cv + sgn * o * sv);
        }
        {  // k half: cols 64..127
          float v = acc[mi][ii + 4][r] + bj[ii + 4];
          float o = __shfl_xor(v, 1);
          K_s[m][ii * 16 + lo] = f2bf(v * cv + sgn * o * sv);
        }
      }
    }
  }
  __syncthreads();

  // ---------------- phase 2: logits = Q @ K^T, mask, scale, store ----------------
  bf16x8 qf[4][2];
#pragma unroll
  for (int mi = 0; mi < 4; ++mi)
#pragma unroll
    for (int ks = 0; ks < 2; ++ks)
      qf[mi][ks] = *reinterpret_cast<const bf16x8*>(&Q_s[w * 64 + mi * 16 + lo][ks * 32 + hi * 8]);

  const size_t outbase = (size_t)bid * (S_LEN * (size_t)S_LEN);
#pragma unroll 1
  for (int nc = 0; nc < 4; ++nc) {
    bf16x8 kf[4][2];
#pragma unroll
    for (int ni = 0; ni < 4; ++ni)
#pragma unroll
      for (int ks = 0; ks < 2; ++ks)
        kf[ni][ks] = *reinterpret_cast<const bf16x8*>(&K_s[nc * 64 + ni * 16 + lo][ks * 32 + hi * 8]);

    f32x4 a2[4][4];
#pragma unroll
    for (int mi = 0; mi < 4; ++mi)
#pragma unroll
      for (int ni = 0; ni < 4; ++ni) a2[mi][ni] = (f32x4){0.f, 0.f, 0.f, 0.f};
#pragma unroll
    for (int ks = 0; ks < 2; ++ks)
#pragma unroll
      for (int mi = 0; mi < 4; ++mi)
#pragma unroll
        for (int ni = 0; ni < 4; ++ni)
          a2[mi][ni] = __builtin_amdgcn_mfma_f32_16x16x32_bf16(qf[mi][ks], kf[ni][ks], a2[mi][ni], 0, 0, 0);

#pragma unroll
    for (int mi = 0; mi < 4; ++mi) {
#pragma unroll
      for (int ni = 0; ni < 4; ++ni) {
        int n = nc * 64 + ni * 16 + lo;
        float pad = mask_s[n];
        float sub = (1.0f - pad) * NEGV;
#pragma unroll
        for (int r = 0; r < 4; ++r) {
          int m = w * 64 + mi * 16 + hi * 4 + r;
          float v = a2[mi][ni][r];
          v = v * pad - sub;
          if (m > n) v -= NEGV;  // tril(.., -1): strictly lower triangle
          out[outbase + (size_t)m * S_LEN + n] = v * 0.125f;  // / sqrt(64)
        }
      }
    }
  }
}

extern "C" void kernel_launch(void* const* d_in, const int* in_sizes, int n_in,
                              void* d_out, int out_size, void* d_ws, size_t ws_size,
                              hipStream_t stream) {
  const float* lhs = (const float*)d_in[0];    // (64,256,768) f32
  const float* Wd = (const float*)d_in[1];     // (768,1664) f32
  const float* bias = (const float*)d_in[2];   // (1664,) f32
  const float* amask = (const float*)d_in[3];  // (64,256) f32
  float* out = (float*)d_out;                  // (64,13,256,256) f32

  dim3 grid(64 * T_HEADS);  // 832 blocks, one per (b, head)
  gp_kernel<<<grid, 256, 0, stream>>>(lhs, Wd, bias, amask, out);
}